// Round 3
// baseline (460.215 us; speedup 1.0000x reference)
//
#include <hip/hip_runtime.h>
#include <hip/hip_bf16.h>

typedef unsigned short u16;
typedef short bf16x8 __attribute__((ext_vector_type(8)));   // 8 bf16 = 4 VGPRs
typedef float f32x4 __attribute__((ext_vector_type(4)));

#define SS_PTS 2048

// workspace byte offsets (all 16B-aligned) — unchanged from R2
#define OFF_IDX   0ULL         // int  [65536*3]
#define OFF_W     786432ULL    // f32  [65536*3]
#define OFF_WT1B  1572864ULL   // bf16 [256][320]
#define OFF_WT2B  1736704ULL   // bf16 [128][256]
#define OFF_ST1   1802240ULL   // f32  [512]
#define OFF_ST2   1804288ULL   // f32  [256]
#define OFF_P1    1805312ULL   // f32  [1024][512]
#define OFF_P2    3902464ULL   // f32  [512][256]
#define OFF_H1    4426752ULL   // bf16 tiled [8][65536][32]
#define OFF_H2    37981184ULL  // bf16 [65536][128]

__device__ __forceinline__ u16 f2bf(float x) {
    union { __hip_bfloat16 h; u16 u; } cv;
    cv.h = __float2bfloat16(x);
    return cv.u;
}
__device__ __forceinline__ float bf2f(u16 u) {
    union { unsigned int i; float f; } cv;
    cv.i = ((unsigned int)u) << 16;
    return cv.f;
}
__device__ __forceinline__ float4 pack8(const float* v) {
    union { u16 u[8]; float4 f; } pk;
    #pragma unroll
    for (int j = 0; j < 8; ++j) pk.u[j] = f2bf(v[j]);
    return pk.f;
}

// ---------------------------------------------------------------- prep: W -> bf16
__global__ __launch_bounds__(256) void prep_kernel(
    const float* __restrict__ W1, const float* __restrict__ W2,
    u16* __restrict__ wt1b, u16* __restrict__ wt2b) {
    int i = blockIdx.x * 256 + threadIdx.x;
    if (i < 81920) wt1b[i] = f2bf(W1[i]);
    if (i < 32768) wt2b[i] = f2bf(W2[i]);
}

// ---------------------------------------------------------------- 3-NN + weights
__global__ __launch_bounds__(256) void knn_kernel(
    const float* __restrict__ xyz1, const float* __restrict__ xyz2,
    int* __restrict__ idxb, float* __restrict__ wb) {
    __shared__ float4 pts[2051];          // 4 regions of 513 (bank stagger)
    __shared__ float cd[64][4][3];
    __shared__ int   ci[64][4][3];
    int t = threadIdx.x;
    int bq = blockIdx.x;
    int b = bq >> 7;
    const float* x2b = xyz2 + (size_t)b * SS_PTS * 3;
    for (int j = t; j < SS_PTS; j += 256) {
        float x = x2b[j * 3 + 0], y = x2b[j * 3 + 1], z = x2b[j * 3 + 2];
        pts[(j >> 9) * 513 + (j & 511)] = make_float4(x, y, z, x * x + y * y + z * z);
    }
    int lq = t >> 2, p = t & 3;
    int g = bq * 64 + lq;
    float qx = xyz1[(size_t)g * 3 + 0];
    float qy = xyz1[(size_t)g * 3 + 1];
    float qz = xyz1[(size_t)g * 3 + 2];
    __syncthreads();

    float m2x = -2.0f * qx, m2y = -2.0f * qy, m2z = -2.0f * qz;
    float d0 = 3.4e38f, d1 = 3.4e38f, d2 = 3.4e38f;
    int j0 = 0, j1 = 0, j2 = 0;
    int base = p * 513, sbase = p * 512;
    #pragma unroll 4
    for (int s = 0; s < 512; ++s) {
        float4 pt = pts[base + s];
        float sc = fmaf(m2x, pt.x, fmaf(m2y, pt.y, fmaf(m2z, pt.z, pt.w)));
        if (sc < d2) {
            d2 = sc; j2 = sbase + s;
            if (d2 < d1) {
                float td = d1; d1 = d2; d2 = td;
                int tj = j1; j1 = j2; j2 = tj;
                if (d1 < d0) {
                    td = d0; d0 = d1; d1 = td;
                    tj = j0; j0 = j1; j1 = tj;
                }
            }
        }
    }
    cd[lq][p][0] = d0; cd[lq][p][1] = d1; cd[lq][p][2] = d2;
    ci[lq][p][0] = j0; ci[lq][p][1] = j1; ci[lq][p][2] = j2;
    __syncthreads();

    if (p == 0) {
        float e0 = 3.4e38f, e1 = 3.4e38f, e2 = 3.4e38f;
        int k0 = 0, k1 = 0, k2 = 0;
        #pragma unroll
        for (int pp = 0; pp < 4; ++pp)
            #pragma unroll
            for (int e = 0; e < 3; ++e) {
                float sc = cd[lq][pp][e];
                int sj = ci[lq][pp][e];
                if (sc < e2) {
                    e2 = sc; k2 = sj;
                    if (e2 < e1) {
                        float td = e1; e1 = e2; e2 = td;
                        int tj = k1; k1 = k2; k2 = tj;
                        if (e1 < e0) {
                            td = e0; e0 = e1; e1 = td;
                            tj = k0; k0 = k1; k1 = tj;
                        }
                    }
                }
            }
        float qq = qx * qx + qy * qy + qz * qz;
        float dd0 = fmaxf(e0 + qq, 1e-10f);
        float dd1 = fmaxf(e1 + qq, 1e-10f);
        float dd2 = fmaxf(e2 + qq, 1e-10f);
        float w0 = 1.0f / dd0, w1 = 1.0f / dd1, w2 = 1.0f / dd2;
        float inv = 1.0f / (w0 + w1 + w2);
        idxb[(size_t)g * 3 + 0] = k0;
        idxb[(size_t)g * 3 + 1] = k1;
        idxb[(size_t)g * 3 + 2] = k2;
        wb[(size_t)g * 3 + 0] = w0 * inv;
        wb[(size_t)g * 3 + 1] = w1 * inv;
        wb[(size_t)g * 3 + 2] = w2 * inv;
    }
}

// ---------------------------------------------------------------- GEMM1 v3
// Block = 64 rows x 256 cols. Phase 1: gather interp (whole K) + points1 into
// LDS once (coalesced). Phase 2: pure LDS+MFMA K-loop, W-tile double-buffered.
// h1 written K-tiled: h1[(c/32)*65536 + row][32] for gemm2 contiguous staging.
__global__ __launch_bounds__(256, 2) void gemm1_kernel(
    const float* __restrict__ points1, const float* __restrict__ points2,
    const int* __restrict__ idxb, const float* __restrict__ wb,
    const u16* __restrict__ wt1b, u16* __restrict__ h1, float* __restrict__ part1) {
    __shared__ __align__(16) u16 Ap[64 * 72];      // p1 part, row stride 72 (pad)
    __shared__ __align__(16) u16 Ai[64 * 264];     // interp, row stride 264 (pad)
    __shared__ __align__(16) u16 Bs[2][8192];      // W1 tile 256x32, XOR-swizzled
    __shared__ int   idxs[192];
    __shared__ float wls[192];
    __shared__ float bsum[256], bsq[256];

    int t = threadIdx.x, bx = blockIdx.x;
    int R0 = bx * 64;
    const float* p2b = points2 + (size_t)(bx >> 7) * SS_PTS * 256;

    if (t < 192) {
        idxs[t] = idxb[(size_t)R0 * 3 + t];
        wls[t]  = wb[(size_t)R0 * 3 + t];
    }
    bsum[t] = 0.0f; bsq[t] = 0.0f;
    __syncthreads();

    // ---- phase 1: materialize A in LDS (once)
    {
        int row = t >> 2, q4 = t & 3;
        // points1: 16 floats per thread
        const float* s = points1 + (size_t)(R0 + row) * 64 + q4 * 16;
        float4 v0 = ((const float4*)s)[0], v1 = ((const float4*)s)[1];
        float4 v2 = ((const float4*)s)[2], v3 = ((const float4*)s)[3];
        float va[16] = {v0.x,v0.y,v0.z,v0.w, v1.x,v1.y,v1.z,v1.w,
                        v2.x,v2.y,v2.z,v2.w, v3.x,v3.y,v3.z,v3.w};
        *(float4*)&Ap[row * 72 + q4 * 16]     = pack8(va);
        *(float4*)&Ap[row * 72 + q4 * 16 + 8] = pack8(va + 8);
        // interp: 64 cols per thread, gathered rows read coalesced (256B/quad)
        int i0 = idxs[row * 3 + 0], i1 = idxs[row * 3 + 1], i2 = idxs[row * 3 + 2];
        float w0 = wls[row * 3 + 0], w1 = wls[row * 3 + 1], w2 = wls[row * 3 + 2];
        const float* r0p = p2b + (size_t)i0 * 256 + q4 * 64;
        const float* r1p = p2b + (size_t)i1 * 256 + q4 * 64;
        const float* r2p = p2b + (size_t)i2 * 256 + q4 * 64;
        u16* dst = &Ai[row * 264 + q4 * 64];
        #pragma unroll 4
        for (int c = 0; c < 8; ++c) {
            float4 a0 = ((const float4*)(r0p + c * 8))[0], a1 = ((const float4*)(r0p + c * 8))[1];
            float4 b0 = ((const float4*)(r1p + c * 8))[0], b1 = ((const float4*)(r1p + c * 8))[1];
            float4 c0 = ((const float4*)(r2p + c * 8))[0], c1 = ((const float4*)(r2p + c * 8))[1];
            float av[8] = {a0.x,a0.y,a0.z,a0.w,a1.x,a1.y,a1.z,a1.w};
            float bv[8] = {b0.x,b0.y,b0.z,b0.w,b1.x,b1.y,b1.z,b1.w};
            float cv[8] = {c0.x,c0.y,c0.z,c0.w,c1.x,c1.y,c1.z,c1.w};
            float ov[8];
            #pragma unroll
            for (int j = 0; j < 8; ++j)
                ov[j] = fmaf(w0, av[j], fmaf(w1, bv[j], w2 * cv[j]));
            *(float4*)&dst[c * 8] = pack8(ov);
        }
    }

    // ---- W-tile staging (XOR swizzle; pattern verified conflict-free in R2)
    int bm = t >> 1, bh = t & 1;
    auto stageB = [&](int buf, int kb) {
        #pragma unroll
        for (int p = 0; p < 2; ++p) {
            int row = bm + p * 128;
            const u16* wsrc = wt1b + (size_t)row * 320 + kb * 32 + bh * 16;
            float4 x0 = ((const float4*)wsrc)[0];
            float4 x1 = ((const float4*)wsrc)[1];
            int s = (row >> 1) & 3;
            *(float4*)&Bs[buf][row * 32 + (((bh * 2 + 0) ^ s) << 3)] = x0;
            *(float4*)&Bs[buf][row * 32 + (((bh * 2 + 1) ^ s) << 3)] = x1;
        }
    };
    stageB(0, 0);
    __syncthreads();

    // ---- phase 2: K-loop (10 x K=32), one barrier per iter
    int w = t >> 6, l = t & 63, l15 = l & 15, q = l >> 4;
    int wr = (w >> 1) * 32, wc = (w & 1) * 128;

    f32x4 acc[2][8];
    #pragma unroll
    for (int i = 0; i < 2; ++i)
        #pragma unroll
        for (int j = 0; j < 8; ++j) acc[i][j] = (f32x4){0.f, 0.f, 0.f, 0.f};

    #pragma unroll
    for (int kb = 0; kb < 10; ++kb) {
        if (kb < 9) stageB((kb + 1) & 1, kb + 1);
        union uf { float4 f; bf16x8 v; };
        uf af[2], bf8[8];
        #pragma unroll
        for (int fi = 0; fi < 2; ++fi) {
            int ml = wr + fi * 16 + l15;
            af[fi].f = (kb < 2)
                ? *(const float4*)&Ap[ml * 72 + kb * 32 + q * 8]
                : *(const float4*)&Ai[ml * 264 + (kb - 2) * 32 + q * 8];
        }
        #pragma unroll
        for (int fj = 0; fj < 8; ++fj) {
            int nl = wc + fj * 16 + l15;
            bf8[fj].f = *(const float4*)&Bs[kb & 1][nl * 32 + ((q ^ ((nl >> 1) & 3)) << 3)];
        }
        #pragma unroll
        for (int fi = 0; fi < 2; ++fi)
            #pragma unroll
            for (int fj = 0; fj < 8; ++fj)
                acc[fi][fj] = __builtin_amdgcn_mfma_f32_16x16x32_bf16(
                    bf8[fj].v, af[fi].v, acc[fi][fj], 0, 0, 0);
        __syncthreads();
    }

    // ---- epilogue: h1 tiled store + channel stats
    #pragma unroll
    for (int fi = 0; fi < 2; ++fi) {
        int rg = R0 + wr + fi * 16 + l15;
        #pragma unroll
        for (int fj = 0; fj < 8; ++fj) {
            int c0 = wc + fj * 16 + q * 4;
            union { u16 u[4]; float2 f; } pk;
            #pragma unroll
            for (int i = 0; i < 4; ++i) pk.u[i] = f2bf(acc[fi][fj][i]);
            *(float2*)&h1[((size_t)(c0 >> 5) * 65536 + rg) * 32 + (c0 & 31)] = pk.f;
        }
    }
    #pragma unroll
    for (int fj = 0; fj < 8; ++fj)
        #pragma unroll
        for (int i = 0; i < 4; ++i) {
            int cl = wc + fj * 16 + q * 4 + i;
            float a0 = acc[0][fj][i], a1 = acc[1][fj][i];
            atomicAdd(&bsum[cl], a0 + a1);
            atomicAdd(&bsq[cl], a0 * a0 + a1 * a1);
        }
    __syncthreads();
    part1[(size_t)bx * 512 + t * 2 + 0] = bsum[t];
    part1[(size_t)bx * 512 + t * 2 + 1] = bsq[t];
}

// ---------------------------------------------------------------- stats reduce
__global__ __launch_bounds__(256) void reduce_kernel(
    const float* __restrict__ part, int nblk, int C, float invM,
    const float* __restrict__ gam, const float* __restrict__ bet,
    float* __restrict__ st) {
    __shared__ float red[256];
    int t = threadIdx.x;
    int slot = t & 31, ig = t >> 5;
    int cb = blockIdx.x * 16;
    float p = 0.0f;
    for (int i = ig; i < nblk; i += 8)
        p += part[(size_t)i * (2 * C) + cb * 2 + slot];
    red[t] = p;
    __syncthreads();
    if (t < 32) {
        float tot = red[t];
        #pragma unroll
        for (int k = 1; k < 8; ++k) tot += red[k * 32 + t];
        red[t] = tot;
    }
    __syncthreads();
    if (t < 16) {
        int c = cb + t;
        float sum = red[2 * t], sq = red[2 * t + 1];
        float mean = sum * invM;
        float var  = sq * invM - mean * mean;
        float rs   = rsqrtf(var + 1e-5f);
        float scv  = gam[c] * rs;
        st[c]     = scv;
        st[C + c] = bet[c] - mean * scv;
    }
}

// ---------------------------------------------------------------- GEMM2 (MFMA)
// A-source: h1 K-tiled -> contiguous 8KB tile loads; BN1+relu fused in staging.
__global__ __launch_bounds__(256) void gemm2_kernel(
    const u16* __restrict__ h1, const u16* __restrict__ wt2b,
    const float* __restrict__ st1,
    u16* __restrict__ h2, float* __restrict__ part2) {
    __shared__ __align__(16) u16 As[128 * 32];
    __shared__ __align__(16) u16 Bs[128 * 32];
    __shared__ float sc1[256], sh1[256];
    __shared__ float bsum[128], bsq[128];

    int t = threadIdx.x;
    int bx = blockIdx.x;
    int R0 = bx * 128;
    sc1[t] = st1[t];
    sh1[t] = st1[256 + t];
    if (t < 128) { bsum[t] = 0.0f; bsq[t] = 0.0f; }

    int m = t >> 1, half = t & 1;
    int sm = (m >> 1) & 3;
    int w = t >> 6, l = t & 63;
    int wr64 = (w >> 1) * 64, wc64 = (w & 1) * 64;
    int l15 = l & 15, q = l >> 4;

    f32x4 acc[4][4];
    #pragma unroll
    for (int i = 0; i < 4; ++i)
        #pragma unroll
        for (int j = 0; j < 4; ++j) acc[i][j] = (f32x4){0.f, 0.f, 0.f, 0.f};

    __syncthreads();

    for (int kb = 0; kb < 256; kb += 32) {
        // ---- stage A from tiled h1: contiguous 8KB per (kb,block)
        {
            const u16* src = h1 + ((size_t)(kb >> 5) * 65536 + R0 + m) * 32 + half * 16;
            union { float4 f; u16 u[8]; } ld0, ld1;
            ld0.f = ((const float4*)src)[0];
            ld1.f = ((const float4*)src)[1];
            int ch0 = kb + half * 16;
            float o0[8], o1[8];
            #pragma unroll
            for (int j = 0; j < 8; ++j) {
                float v = fmaf(bf2f(ld0.u[j]), sc1[ch0 + j], sh1[ch0 + j]);
                o0[j] = fmaxf(v, 0.0f);
            }
            #pragma unroll
            for (int j = 0; j < 8; ++j) {
                float v = fmaf(bf2f(ld1.u[j]), sc1[ch0 + 8 + j], sh1[ch0 + 8 + j]);
                o1[j] = fmaxf(v, 0.0f);
            }
            *(float4*)&As[m * 32 + (((half * 2 + 0) ^ sm) << 3)] = pack8(o0);
            *(float4*)&As[m * 32 + (((half * 2 + 1) ^ sm) << 3)] = pack8(o1);
        }
        // ---- stage B
        {
            const u16* wsrc = wt2b + (size_t)m * 256 + kb + half * 16;
            float4 w0 = ((const float4*)wsrc)[0];
            float4 w1 = ((const float4*)wsrc)[1];
            *(float4*)&Bs[m * 32 + (((half * 2 + 0) ^ sm) << 3)] = w0;
            *(float4*)&Bs[m * 32 + (((half * 2 + 1) ^ sm) << 3)] = w1;
        }
        __syncthreads();

        union uf { float4 f; bf16x8 v; };
        uf af[4], bfr[4];
        #pragma unroll
        for (int fi = 0; fi < 4; ++fi) {
            int ml = wr64 + fi * 16 + l15;
            af[fi].f = *(const float4*)&As[ml * 32 + ((q ^ ((ml >> 1) & 3)) << 3)];
        }
        #pragma unroll
        for (int fj = 0; fj < 4; ++fj) {
            int nl = wc64 + fj * 16 + l15;
            bfr[fj].f = *(const float4*)&Bs[nl * 32 + ((q ^ ((nl >> 1) & 3)) << 3)];
        }
        #pragma unroll
        for (int fi = 0; fi < 4; ++fi)
            #pragma unroll
            for (int fj = 0; fj < 4; ++fj)
                acc[fi][fj] = __builtin_amdgcn_mfma_f32_16x16x32_bf16(
                    bfr[fj].v, af[fi].v, acc[fi][fj], 0, 0, 0);
        __syncthreads();
    }

    #pragma unroll
    for (int fi = 0; fi < 4; ++fi) {
        int rg = R0 + wr64 + fi * 16 + l15;
        #pragma unroll
        for (int fj = 0; fj < 4; ++fj) {
            int cl = wc64 + fj * 16 + q * 4;
            union { u16 u[4]; float2 f; } pk;
            #pragma unroll
            for (int i = 0; i < 4; ++i) pk.u[i] = f2bf(acc[fi][fj][i]);
            *(float2*)&h2[(size_t)rg * 128 + cl] = pk.f;
        }
    }
    #pragma unroll
    for (int fj = 0; fj < 4; ++fj)
        #pragma unroll
        for (int i = 0; i < 4; ++i) {
            int cl = wc64 + fj * 16 + q * 4 + i;
            float s = acc[0][fj][i] + acc[1][fj][i] + acc[2][fj][i] + acc[3][fj][i];
            float sq = acc[0][fj][i]*acc[0][fj][i] + acc[1][fj][i]*acc[1][fj][i]
                     + acc[2][fj][i]*acc[2][fj][i] + acc[3][fj][i]*acc[3][fj][i];
            atomicAdd(&bsum[cl], s);
            atomicAdd(&bsq[cl], sq);
        }
    __syncthreads();
    if (t < 128) {
        part2[(size_t)bx * 256 + t * 2 + 0] = bsum[t];
        part2[(size_t)bx * 256 + t * 2 + 1] = bsq[t];
    }
}

// ---------------------------------------------------------------- final BN2 + relu
__global__ __launch_bounds__(256) void final_kernel(
    const u16* __restrict__ h2, const float* __restrict__ st2,
    float* __restrict__ out) {
    __shared__ float lst[256];
    int t = threadIdx.x;
    lst[t] = st2[t];
    __syncthreads();
    size_t e0 = ((size_t)blockIdx.x * 256 + t) * 8;
    int c0 = (int)(e0 & 127);
    union { float4 f; u16 u[8]; } ld;
    ld.f = *(const float4*)(h2 + e0);
    float o[8];
    #pragma unroll
    for (int j = 0; j < 8; ++j) {
        int c = c0 + j;
        float v = fmaf(bf2f(ld.u[j]), lst[c], lst[128 + c]);
        o[j] = fmaxf(v, 0.0f);
    }
    float4* op = (float4*)(out + e0);
    float4 r0; r0.x = o[0]; r0.y = o[1]; r0.z = o[2]; r0.w = o[3];
    float4 r1; r1.x = o[4]; r1.y = o[5]; r1.z = o[6]; r1.w = o[7];
    op[0] = r0;
    op[1] = r1;
}

// ----------------------------------------------------------------
extern "C" void kernel_launch(void* const* d_in, const int* in_sizes, int n_in,
                              void* d_out, int out_size, void* d_ws, size_t ws_size,
                              hipStream_t stream) {
    (void)in_sizes; (void)n_in; (void)out_size; (void)ws_size;
    const float* xyz1    = (const float*)d_in[0];
    const float* xyz2    = (const float*)d_in[1];
    const float* points1 = (const float*)d_in[2];
    const float* points2 = (const float*)d_in[3];
    const float* W1      = (const float*)d_in[4];
    const float* g1      = (const float*)d_in[5];
    const float* b1      = (const float*)d_in[6];
    const float* W2      = (const float*)d_in[7];
    const float* g2      = (const float*)d_in[8];
    const float* b2      = (const float*)d_in[9];

    char* ws = (char*)d_ws;
    int*   idxb = (int*)(ws + OFF_IDX);
    float* wb   = (float*)(ws + OFF_W);
    u16*   wt1b = (u16*)(ws + OFF_WT1B);
    u16*   wt2b = (u16*)(ws + OFF_WT2B);
    float* st1  = (float*)(ws + OFF_ST1);
    float* st2  = (float*)(ws + OFF_ST2);
    float* p1   = (float*)(ws + OFF_P1);
    float* p2   = (float*)(ws + OFF_P2);
    u16*   h1   = (u16*)(ws + OFF_H1);
    u16*   h2   = (u16*)(ws + OFF_H2);
    float* outp = (float*)d_out;

    prep_kernel<<<320, 256, 0, stream>>>(W1, W2, wt1b, wt2b);
    knn_kernel<<<1024, 256, 0, stream>>>(xyz1, xyz2, idxb, wb);
    gemm1_kernel<<<1024, 256, 0, stream>>>(points1, points2, idxb, wb, wt1b, h1, p1);
    reduce_kernel<<<16, 256, 0, stream>>>(p1, 1024, 256, 1.0f / 65536.0f, g1, b1, st1);
    gemm2_kernel<<<512, 256, 0, stream>>>(h1, wt2b, st1, h2, p2);
    reduce_kernel<<<8, 256, 0, stream>>>(p2, 512, 128, 1.0f / 65536.0f, g2, b2, st2);
    final_kernel<<<4096, 256, 0, stream>>>(h2, st2, outp);
}

// Round 4
// 442.834 us; speedup vs baseline: 1.0393x; 1.0393x over previous
//
#include <hip/hip_runtime.h>
#include <hip/hip_bf16.h>

typedef unsigned short u16;
typedef short bf16x8 __attribute__((ext_vector_type(8)));   // 8 bf16 = 4 VGPRs
typedef float f32x4 __attribute__((ext_vector_type(4)));

#define SS_PTS 2048

// workspace byte offsets (all 16B-aligned)
#define OFF_IDX   0ULL         // int  [65536*3]
#define OFF_W     786432ULL    // f32  [65536*3]
#define OFF_WT1B  1572864ULL   // bf16 [256][320]
#define OFF_WT2B  1736704ULL   // bf16 [128][256]
#define OFF_ST1   1802240ULL   // f32  [512]
#define OFF_ST2   1804288ULL   // f32  [256]
#define OFF_P1    1805312ULL   // f32  [1024][512]
#define OFF_P2    3902464ULL   // f32  [1024][256]
#define OFF_H1    4950016ULL   // bf16 tiled [8][65536][32]
#define OFF_H2    38504448ULL  // bf16 [65536][128]

__device__ __forceinline__ u16 f2bf(float x) {
    union { __hip_bfloat16 h; u16 u; } cv;
    cv.h = __float2bfloat16(x);
    return cv.u;
}
__device__ __forceinline__ float bf2f(u16 u) {
    union { unsigned int i; float f; } cv;
    cv.i = ((unsigned int)u) << 16;
    return cv.f;
}
__device__ __forceinline__ float4 pack8(const float* v) {
    union { u16 u[8]; float4 f; } pk;
    #pragma unroll
    for (int j = 0; j < 8; ++j) pk.u[j] = f2bf(v[j]);
    return pk.f;
}

// ---------------------------------------------------------------- prep: W -> bf16
__global__ __launch_bounds__(256) void prep_kernel(
    const float* __restrict__ W1, const float* __restrict__ W2,
    u16* __restrict__ wt1b, u16* __restrict__ wt2b) {
    int i = blockIdx.x * 256 + threadIdx.x;
    if (i < 81920) wt1b[i] = f2bf(W1[i]);
    if (i < 32768) wt2b[i] = f2bf(W2[i]);
}

// ---------------------------------------------------------------- 3-NN + weights
__global__ __launch_bounds__(256) void knn_kernel(
    const float* __restrict__ xyz1, const float* __restrict__ xyz2,
    int* __restrict__ idxb, float* __restrict__ wb) {
    __shared__ float4 pts[2051];          // 4 regions of 513 (bank stagger)
    __shared__ float cd[64][4][3];
    __shared__ int   ci[64][4][3];
    int t = threadIdx.x;
    int bq = blockIdx.x;
    int b = bq >> 7;
    const float* x2b = xyz2 + (size_t)b * SS_PTS * 3;
    for (int j = t; j < SS_PTS; j += 256) {
        float x = x2b[j * 3 + 0], y = x2b[j * 3 + 1], z = x2b[j * 3 + 2];
        pts[(j >> 9) * 513 + (j & 511)] = make_float4(x, y, z, x * x + y * y + z * z);
    }
    int lq = t >> 2, p = t & 3;
    int g = bq * 64 + lq;
    float qx = xyz1[(size_t)g * 3 + 0];
    float qy = xyz1[(size_t)g * 3 + 1];
    float qz = xyz1[(size_t)g * 3 + 2];
    __syncthreads();

    float m2x = -2.0f * qx, m2y = -2.0f * qy, m2z = -2.0f * qz;
    float d0 = 3.4e38f, d1 = 3.4e38f, d2 = 3.4e38f;
    int j0 = 0, j1 = 0, j2 = 0;
    int base = p * 513, sbase = p * 512;
    #pragma unroll 4
    for (int s = 0; s < 512; ++s) {
        float4 pt = pts[base + s];
        float sc = fmaf(m2x, pt.x, fmaf(m2y, pt.y, fmaf(m2z, pt.z, pt.w)));
        if (sc < d2) {
            d2 = sc; j2 = sbase + s;
            if (d2 < d1) {
                float td = d1; d1 = d2; d2 = td;
                int tj = j1; j1 = j2; j2 = tj;
                if (d1 < d0) {
                    td = d0; d0 = d1; d1 = td;
                    tj = j0; j0 = j1; j1 = tj;
                }
            }
        }
    }
    cd[lq][p][0] = d0; cd[lq][p][1] = d1; cd[lq][p][2] = d2;
    ci[lq][p][0] = j0; ci[lq][p][1] = j1; ci[lq][p][2] = j2;
    __syncthreads();

    if (p == 0) {
        float e0 = 3.4e38f, e1 = 3.4e38f, e2 = 3.4e38f;
        int k0 = 0, k1 = 0, k2 = 0;
        #pragma unroll
        for (int pp = 0; pp < 4; ++pp)
            #pragma unroll
            for (int e = 0; e < 3; ++e) {
                float sc = cd[lq][pp][e];
                int sj = ci[lq][pp][e];
                if (sc < e2) {
                    e2 = sc; k2 = sj;
                    if (e2 < e1) {
                        float td = e1; e1 = e2; e2 = td;
                        int tj = k1; k1 = k2; k2 = tj;
                        if (e1 < e0) {
                            td = e0; e0 = e1; e1 = td;
                            tj = k0; k0 = k1; k1 = tj;
                        }
                    }
                }
            }
        float qq = qx * qx + qy * qy + qz * qz;
        float dd0 = fmaxf(e0 + qq, 1e-10f);
        float dd1 = fmaxf(e1 + qq, 1e-10f);
        float dd2 = fmaxf(e2 + qq, 1e-10f);
        float w0 = 1.0f / dd0, w1 = 1.0f / dd1, w2 = 1.0f / dd2;
        float inv = 1.0f / (w0 + w1 + w2);
        idxb[(size_t)g * 3 + 0] = k0;
        idxb[(size_t)g * 3 + 1] = k1;
        idxb[(size_t)g * 3 + 2] = k2;
        wb[(size_t)g * 3 + 0] = w0 * inv;
        wb[(size_t)g * 3 + 1] = w1 * inv;
        wb[(size_t)g * 3 + 2] = w2 * inv;
    }
}

// ---------------------------------------------------------------- GEMM1 v4
// 64 rows x 256 cols/block. Phase 1: gather interp + points1 into LDS once.
// Phase 2: LDS+MFMA K-loop, single-buffered W tile (2 barriers/iter).
// LDS ~61.5 KB -> 2 blocks/CU (the R3 regression was 79.5 KB -> 1 block/CU).
__global__ __launch_bounds__(256, 2) void gemm1_kernel(
    const float* __restrict__ points1, const float* __restrict__ points2,
    const int* __restrict__ idxb, const float* __restrict__ wb,
    const u16* __restrict__ wt1b, u16* __restrict__ h1, float* __restrict__ part1) {
    __shared__ __align__(16) u16 Ap[64 * 72];      // points1 bf16, stride 72
    __shared__ __align__(16) u16 Ai[64 * 264];     // interp bf16, stride 264
    __shared__ __align__(16) u16 Bs[8192];         // W1 tile 256x32, XOR-swizzled
    __shared__ int   idxs[192];
    __shared__ float wls[192];
    __shared__ float bsum[256], bsq[256];

    int t = threadIdx.x, bx = blockIdx.x;
    int R0 = bx * 64;
    const float* p2b = points2 + (size_t)(bx >> 7) * SS_PTS * 256;

    if (t < 192) {
        idxs[t] = idxb[(size_t)R0 * 3 + t];
        wls[t]  = wb[(size_t)R0 * 3 + t];
    }
    bsum[t] = 0.0f; bsq[t] = 0.0f;
    __syncthreads();

    // ---- phase 1: materialize A in LDS (once, coalesced)
    {
        int row = t >> 2, q4 = t & 3;
        const float* s = points1 + (size_t)(R0 + row) * 64 + q4 * 16;
        float4 v0 = ((const float4*)s)[0], v1 = ((const float4*)s)[1];
        float4 v2 = ((const float4*)s)[2], v3 = ((const float4*)s)[3];
        float va[16] = {v0.x,v0.y,v0.z,v0.w, v1.x,v1.y,v1.z,v1.w,
                        v2.x,v2.y,v2.z,v2.w, v3.x,v3.y,v3.z,v3.w};
        *(float4*)&Ap[row * 72 + q4 * 16]     = pack8(va);
        *(float4*)&Ap[row * 72 + q4 * 16 + 8] = pack8(va + 8);
        int i0 = idxs[row * 3 + 0], i1 = idxs[row * 3 + 1], i2 = idxs[row * 3 + 2];
        float w0 = wls[row * 3 + 0], w1 = wls[row * 3 + 1], w2 = wls[row * 3 + 2];
        const float* r0p = p2b + (size_t)i0 * 256 + q4 * 64;
        const float* r1p = p2b + (size_t)i1 * 256 + q4 * 64;
        const float* r2p = p2b + (size_t)i2 * 256 + q4 * 64;
        u16* dst = &Ai[row * 264 + q4 * 64];
        #pragma unroll 4
        for (int c = 0; c < 8; ++c) {
            float4 a0 = ((const float4*)(r0p + c * 8))[0], a1 = ((const float4*)(r0p + c * 8))[1];
            float4 b0 = ((const float4*)(r1p + c * 8))[0], b1 = ((const float4*)(r1p + c * 8))[1];
            float4 c0 = ((const float4*)(r2p + c * 8))[0], c1 = ((const float4*)(r2p + c * 8))[1];
            float av[8] = {a0.x,a0.y,a0.z,a0.w,a1.x,a1.y,a1.z,a1.w};
            float bv[8] = {b0.x,b0.y,b0.z,b0.w,b1.x,b1.y,b1.z,b1.w};
            float cv[8] = {c0.x,c0.y,c0.z,c0.w,c1.x,c1.y,c1.z,c1.w};
            float ov[8];
            #pragma unroll
            for (int j = 0; j < 8; ++j)
                ov[j] = fmaf(w0, av[j], fmaf(w1, bv[j], w2 * cv[j]));
            *(float4*)&dst[c * 8] = pack8(ov);
        }
    }

    int bm = t >> 1, bh = t & 1;
    int w = t >> 6, l = t & 63, l15 = l & 15, q = l >> 4;
    int wr = (w >> 1) * 32, wc = (w & 1) * 128;

    f32x4 acc[2][8];
    #pragma unroll
    for (int i = 0; i < 2; ++i)
        #pragma unroll
        for (int j = 0; j < 8; ++j) acc[i][j] = (f32x4){0.f, 0.f, 0.f, 0.f};

    // ---- phase 2: K-loop (10 x K=32), single-buffer B, 2 barriers/iter
    #pragma unroll
    for (int kb = 0; kb < 10; ++kb) {
        #pragma unroll
        for (int p = 0; p < 2; ++p) {
            int row = bm + p * 128;
            const u16* wsrc = wt1b + (size_t)row * 320 + kb * 32 + bh * 16;
            float4 x0 = ((const float4*)wsrc)[0];
            float4 x1 = ((const float4*)wsrc)[1];
            int s = (row >> 1) & 3;
            *(float4*)&Bs[row * 32 + (((bh * 2 + 0) ^ s) << 3)] = x0;
            *(float4*)&Bs[row * 32 + (((bh * 2 + 1) ^ s) << 3)] = x1;
        }
        __syncthreads();
        union uf { float4 f; bf16x8 v; };
        uf af[2], bf8[8];
        #pragma unroll
        for (int fi = 0; fi < 2; ++fi) {
            int ml = wr + fi * 16 + l15;
            af[fi].f = (kb < 2)
                ? *(const float4*)&Ap[ml * 72 + kb * 32 + q * 8]
                : *(const float4*)&Ai[ml * 264 + (kb - 2) * 32 + q * 8];
        }
        #pragma unroll
        for (int fj = 0; fj < 8; ++fj) {
            int nl = wc + fj * 16 + l15;
            bf8[fj].f = *(const float4*)&Bs[nl * 32 + ((q ^ ((nl >> 1) & 3)) << 3)];
        }
        #pragma unroll
        for (int fi = 0; fi < 2; ++fi)
            #pragma unroll
            for (int fj = 0; fj < 8; ++fj)
                acc[fi][fj] = __builtin_amdgcn_mfma_f32_16x16x32_bf16(
                    bf8[fj].v, af[fi].v, acc[fi][fj], 0, 0, 0);
        __syncthreads();
    }

    // ---- epilogue: h1 K-tiled store + channel stats
    #pragma unroll
    for (int fi = 0; fi < 2; ++fi) {
        int rg = R0 + wr + fi * 16 + l15;
        #pragma unroll
        for (int fj = 0; fj < 8; ++fj) {
            int c0 = wc + fj * 16 + q * 4;
            union { u16 u[4]; float2 f; } pk;
            #pragma unroll
            for (int i = 0; i < 4; ++i) pk.u[i] = f2bf(acc[fi][fj][i]);
            *(float2*)&h1[((size_t)(c0 >> 5) * 65536 + rg) * 32 + (c0 & 31)] = pk.f;
        }
    }
    #pragma unroll
    for (int fj = 0; fj < 8; ++fj)
        #pragma unroll
        for (int i = 0; i < 4; ++i) {
            int cl = wc + fj * 16 + q * 4 + i;
            float a0 = acc[0][fj][i], a1 = acc[1][fj][i];
            atomicAdd(&bsum[cl], a0 + a1);
            atomicAdd(&bsq[cl], a0 * a0 + a1 * a1);
        }
    __syncthreads();
    part1[(size_t)bx * 512 + t * 2 + 0] = bsum[t];
    part1[(size_t)bx * 512 + t * 2 + 1] = bsq[t];
}

// ---------------------------------------------------------------- stats reduce
__global__ __launch_bounds__(256) void reduce_kernel(
    const float* __restrict__ part, int nblk, int C, float invM,
    const float* __restrict__ gam, const float* __restrict__ bet,
    float* __restrict__ st) {
    __shared__ float red[256];
    int t = threadIdx.x;
    int slot = t & 31, ig = t >> 5;
    int cb = blockIdx.x * 16;
    float p = 0.0f;
    for (int i = ig; i < nblk; i += 8)
        p += part[(size_t)i * (2 * C) + cb * 2 + slot];
    red[t] = p;
    __syncthreads();
    if (t < 32) {
        float tot = red[t];
        #pragma unroll
        for (int k = 1; k < 8; ++k) tot += red[k * 32 + t];
        red[t] = tot;
    }
    __syncthreads();
    if (t < 16) {
        int c = cb + t;
        float sum = red[2 * t], sq = red[2 * t + 1];
        float mean = sum * invM;
        float var  = sq * invM - mean * mean;
        float rs   = rsqrtf(var + 1e-5f);
        float scv  = gam[c] * rs;
        st[c]     = scv;
        st[C + c] = bet[c] - mean * scv;
    }
}

// ---------------------------------------------------------------- GEMM2 v4
// 64x128 tile, grid 1024 (4 blocks/CU). A from K-tiled h1, BN1+relu in staging.
__global__ __launch_bounds__(256) void gemm2_kernel(
    const u16* __restrict__ h1, const u16* __restrict__ wt2b,
    const float* __restrict__ st1,
    u16* __restrict__ h2, float* __restrict__ part2) {
    __shared__ __align__(16) u16 As[64 * 32];
    __shared__ __align__(16) u16 Bs[128 * 32];
    __shared__ float sc1[256], sh1[256];
    __shared__ float bsum[128], bsq[128];

    int t = threadIdx.x;
    int bx = blockIdx.x;
    int R0 = bx * 64;
    sc1[t] = st1[t];
    sh1[t] = st1[256 + t];
    if (t < 128) { bsum[t] = 0.0f; bsq[t] = 0.0f; }

    int w = t >> 6, l = t & 63, l15 = l & 15, q = l >> 4;
    int wr = w * 16;

    f32x4 acc[8];
    #pragma unroll
    for (int j = 0; j < 8; ++j) acc[j] = (f32x4){0.f, 0.f, 0.f, 0.f};

    __syncthreads();

    for (int kb = 0; kb < 256; kb += 32) {
        // ---- stage A (64 rows x 32 cols) from K-tiled h1, fused BN1+relu
        {
            int row = t >> 2, c8 = (t & 3) << 3;
            const u16* src = h1 + ((size_t)(kb >> 5) * 65536 + R0 + row) * 32 + c8;
            union { float4 f; u16 u[8]; } ld;
            ld.f = *(const float4*)src;
            int ch0 = kb + c8;
            float o[8];
            #pragma unroll
            for (int j = 0; j < 8; ++j) {
                float v = fmaf(bf2f(ld.u[j]), sc1[ch0 + j], sh1[ch0 + j]);
                o[j] = fmaxf(v, 0.0f);
            }
            int s = (row >> 1) & 3;
            *(float4*)&As[row * 32 + (((c8 >> 3) ^ s) << 3)] = pack8(o);
        }
        // ---- stage B (128 rows x 32 cols)
        {
            int m = t >> 1, half = t & 1;
            const u16* wsrc = wt2b + (size_t)m * 256 + kb + half * 16;
            float4 w0 = ((const float4*)wsrc)[0];
            float4 w1 = ((const float4*)wsrc)[1];
            int s = (m >> 1) & 3;
            *(float4*)&Bs[m * 32 + (((half * 2 + 0) ^ s) << 3)] = w0;
            *(float4*)&Bs[m * 32 + (((half * 2 + 1) ^ s) << 3)] = w1;
        }
        __syncthreads();

        union uf { float4 f; bf16x8 v; };
        uf af, bf8[8];
        {
            int ml = wr + l15;
            af.f = *(const float4*)&As[ml * 32 + ((q ^ ((ml >> 1) & 3)) << 3)];
        }
        #pragma unroll
        for (int fj = 0; fj < 8; ++fj) {
            int nl = fj * 16 + l15;
            bf8[fj].f = *(const float4*)&Bs[nl * 32 + ((q ^ ((nl >> 1) & 3)) << 3)];
        }
        #pragma unroll
        for (int fj = 0; fj < 8; ++fj)
            acc[fj] = __builtin_amdgcn_mfma_f32_16x16x32_bf16(
                bf8[fj].v, af.v, acc[fj], 0, 0, 0);
        __syncthreads();
    }

    // ---- epilogue: h2 row-major store + stats (shfl-reduce over 16 row-lanes)
    int rg = R0 + wr + l15;
    #pragma unroll
    for (int fj = 0; fj < 8; ++fj) {
        int cl = fj * 16 + q * 4;
        union { u16 u[4]; float2 f; } pk;
        #pragma unroll
        for (int i = 0; i < 4; ++i) pk.u[i] = f2bf(acc[fj][i]);
        *(float2*)&h2[(size_t)rg * 128 + cl] = pk.f;
    }
    #pragma unroll
    for (int fj = 0; fj < 8; ++fj)
        #pragma unroll
        for (int i = 0; i < 4; ++i) {
            float s = acc[fj][i];
            float sq = s * s;
            #pragma unroll
            for (int d = 1; d < 16; d <<= 1) {
                s  += __shfl_xor(s, d, 16);
                sq += __shfl_xor(sq, d, 16);
            }
            if (l15 == 0) {
                int cl = fj * 16 + q * 4 + i;
                atomicAdd(&bsum[cl], s);
                atomicAdd(&bsq[cl], sq);
            }
        }
    __syncthreads();
    if (t < 128) {
        part2[(size_t)bx * 256 + t * 2 + 0] = bsum[t];
        part2[(size_t)bx * 256 + t * 2 + 1] = bsq[t];
    }
}

// ---------------------------------------------------------------- final BN2 + relu
__global__ __launch_bounds__(256) void final_kernel(
    const u16* __restrict__ h2, const float* __restrict__ st2,
    float* __restrict__ out) {
    __shared__ float lst[256];
    int t = threadIdx.x;
    lst[t] = st2[t];
    __syncthreads();
    size_t e0 = ((size_t)blockIdx.x * 256 + t) * 8;
    int c0 = (int)(e0 & 127);
    union { float4 f; u16 u[8]; } ld;
    ld.f = *(const float4*)(h2 + e0);
    float o[8];
    #pragma unroll
    for (int j = 0; j < 8; ++j) {
        int c = c0 + j;
        float v = fmaf(bf2f(ld.u[j]), lst[c], lst[128 + c]);
        o[j] = fmaxf(v, 0.0f);
    }
    float4* op = (float4*)(out + e0);
    float4 r0; r0.x = o[0]; r0.y = o[1]; r0.z = o[2]; r0.w = o[3];
    float4 r1; r1.x = o[4]; r1.y = o[5]; r1.z = o[6]; r1.w = o[7];
    op[0] = r0;
    op[1] = r1;
}

// ----------------------------------------------------------------
extern "C" void kernel_launch(void* const* d_in, const int* in_sizes, int n_in,
                              void* d_out, int out_size, void* d_ws, size_t ws_size,
                              hipStream_t stream) {
    (void)in_sizes; (void)n_in; (void)out_size; (void)ws_size;
    const float* xyz1    = (const float*)d_in[0];
    const float* xyz2    = (const float*)d_in[1];
    const float* points1 = (const float*)d_in[2];
    const float* points2 = (const float*)d_in[3];
    const float* W1      = (const float*)d_in[4];
    const float* g1      = (const float*)d_in[5];
    const float* b1      = (const float*)d_in[6];
    const float* W2      = (const float*)d_in[7];
    const float* g2      = (const float*)d_in[8];
    const float* b2      = (const float*)d_in[9];

    char* ws = (char*)d_ws;
    int*   idxb = (int*)(ws + OFF_IDX);
    float* wb   = (float*)(ws + OFF_W);
    u16*   wt1b = (u16*)(ws + OFF_WT1B);
    u16*   wt2b = (u16*)(ws + OFF_WT2B);
    float* st1  = (float*)(ws + OFF_ST1);
    float* st2  = (float*)(ws + OFF_ST2);
    float* p1   = (float*)(ws + OFF_P1);
    float* p2   = (float*)(ws + OFF_P2);
    u16*   h1   = (u16*)(ws + OFF_H1);
    u16*   h2   = (u16*)(ws + OFF_H2);
    float* outp = (float*)d_out;

    prep_kernel<<<320, 256, 0, stream>>>(W1, W2, wt1b, wt2b);
    knn_kernel<<<1024, 256, 0, stream>>>(xyz1, xyz2, idxb, wb);
    gemm1_kernel<<<1024, 256, 0, stream>>>(points1, points2, idxb, wb, wt1b, h1, p1);
    reduce_kernel<<<16, 256, 0, stream>>>(p1, 1024, 256, 1.0f / 65536.0f, g1, b1, st1);
    gemm2_kernel<<<1024, 256, 0, stream>>>(h1, wt2b, st1, h2, p2);
    reduce_kernel<<<8, 256, 0, stream>>>(p2, 1024, 128, 1.0f / 65536.0f, g2, b2, st2);
    final_kernel<<<4096, 256, 0, stream>>>(h2, st2, outp);
}

// Round 5
// 423.782 us; speedup vs baseline: 1.0860x; 1.0450x over previous
//
#include <hip/hip_runtime.h>
#include <hip/hip_bf16.h>

typedef unsigned short u16;
typedef short bf16x8 __attribute__((ext_vector_type(8)));   // 8 bf16 = 4 VGPRs
typedef float f32x4 __attribute__((ext_vector_type(4)));

#define SS_PTS 2048

// workspace byte offsets (all 16B-aligned)
#define OFF_IDX   0ULL         // int  [65536*3]
#define OFF_W     786432ULL    // f32  [65536*3]
#define OFF_WT1B  1572864ULL   // bf16 [256][320]
#define OFF_WT2B  1736704ULL   // bf16 [128][256]
#define OFF_ST1   1802240ULL   // f32  [512]
#define OFF_ST2   1804288ULL   // f32  [256]
#define OFF_P1    1805312ULL   // f32  [1024][512]
#define OFF_P2    3902464ULL   // f32  [1024][256]
#define OFF_H1    4950016ULL   // bf16 tiled [8][65536][32]
#define OFF_H2    38504448ULL  // bf16 [65536][128]

__device__ __forceinline__ u16 f2bf(float x) {
    union { __hip_bfloat16 h; u16 u; } cv;
    cv.h = __float2bfloat16(x);
    return cv.u;
}
__device__ __forceinline__ float bf2f(u16 u) {
    union { unsigned int i; float f; } cv;
    cv.i = ((unsigned int)u) << 16;
    return cv.f;
}
__device__ __forceinline__ float4 pack8(const float* v) {
    union { u16 u[8]; float4 f; } pk;
    #pragma unroll
    for (int j = 0; j < 8; ++j) pk.u[j] = f2bf(v[j]);
    return pk.f;
}

// ---------------------------------------------------------------- prep: W -> bf16
__global__ __launch_bounds__(256) void prep_kernel(
    const float* __restrict__ W1, const float* __restrict__ W2,
    u16* __restrict__ wt1b, u16* __restrict__ wt2b) {
    int i = blockIdx.x * 256 + threadIdx.x;
    if (i < 81920) wt1b[i] = f2bf(W1[i]);
    if (i < 32768) wt2b[i] = f2bf(W2[i]);
}

// ---------------------------------------------------------------- 3-NN + weights
__global__ __launch_bounds__(256) void knn_kernel(
    const float* __restrict__ xyz1, const float* __restrict__ xyz2,
    int* __restrict__ idxb, float* __restrict__ wb) {
    __shared__ float4 pts[2051];          // 4 regions of 513 (bank stagger)
    __shared__ float cd[64][4][3];
    __shared__ int   ci[64][4][3];
    int t = threadIdx.x;
    int bq = blockIdx.x;
    int b = bq >> 7;
    const float* x2b = xyz2 + (size_t)b * SS_PTS * 3;
    for (int j = t; j < SS_PTS; j += 256) {
        float x = x2b[j * 3 + 0], y = x2b[j * 3 + 1], z = x2b[j * 3 + 2];
        pts[(j >> 9) * 513 + (j & 511)] = make_float4(x, y, z, x * x + y * y + z * z);
    }
    int lq = t >> 2, p = t & 3;
    int g = bq * 64 + lq;
    float qx = xyz1[(size_t)g * 3 + 0];
    float qy = xyz1[(size_t)g * 3 + 1];
    float qz = xyz1[(size_t)g * 3 + 2];
    __syncthreads();

    float m2x = -2.0f * qx, m2y = -2.0f * qy, m2z = -2.0f * qz;
    float d0 = 3.4e38f, d1 = 3.4e38f, d2 = 3.4e38f;
    int j0 = 0, j1 = 0, j2 = 0;
    int base = p * 513, sbase = p * 512;
    #pragma unroll 4
    for (int s = 0; s < 512; ++s) {
        float4 pt = pts[base + s];
        float sc = fmaf(m2x, pt.x, fmaf(m2y, pt.y, fmaf(m2z, pt.z, pt.w)));
        if (sc < d2) {
            d2 = sc; j2 = sbase + s;
            if (d2 < d1) {
                float td = d1; d1 = d2; d2 = td;
                int tj = j1; j1 = j2; j2 = tj;
                if (d1 < d0) {
                    td = d0; d0 = d1; d1 = td;
                    tj = j0; j0 = j1; j1 = tj;
                }
            }
        }
    }
    cd[lq][p][0] = d0; cd[lq][p][1] = d1; cd[lq][p][2] = d2;
    ci[lq][p][0] = j0; ci[lq][p][1] = j1; ci[lq][p][2] = j2;
    __syncthreads();

    if (p == 0) {
        float e0 = 3.4e38f, e1 = 3.4e38f, e2 = 3.4e38f;
        int k0 = 0, k1 = 0, k2 = 0;
        #pragma unroll
        for (int pp = 0; pp < 4; ++pp)
            #pragma unroll
            for (int e = 0; e < 3; ++e) {
                float sc = cd[lq][pp][e];
                int sj = ci[lq][pp][e];
                if (sc < e2) {
                    e2 = sc; k2 = sj;
                    if (e2 < e1) {
                        float td = e1; e1 = e2; e2 = td;
                        int tj = k1; k1 = k2; k2 = tj;
                        if (e1 < e0) {
                            td = e0; e0 = e1; e1 = td;
                            tj = k0; k0 = k1; k1 = tj;
                        }
                    }
                }
            }
        float qq = qx * qx + qy * qy + qz * qz;
        float dd0 = fmaxf(e0 + qq, 1e-10f);
        float dd1 = fmaxf(e1 + qq, 1e-10f);
        float dd2 = fmaxf(e2 + qq, 1e-10f);
        float w0 = 1.0f / dd0, w1 = 1.0f / dd1, w2 = 1.0f / dd2;
        float inv = 1.0f / (w0 + w1 + w2);
        idxb[(size_t)g * 3 + 0] = k0;
        idxb[(size_t)g * 3 + 1] = k1;
        idxb[(size_t)g * 3 + 2] = k2;
        wb[(size_t)g * 3 + 0] = w0 * inv;
        wb[(size_t)g * 3 + 1] = w1 * inv;
        wb[(size_t)g * 3 + 2] = w2 * inv;
    }
}

// ---------------------------------------------------------------- GEMM1 v5
// 64 rows x 256 cols/block. Phase 1: WAVE-COALESCED gather — one wave reads one
// 1KB points2 row per instruction (64 lanes x 16B), combines 3 neighbors
// in-register, writes interp to K-tiled swizzled LDS (AiT). points1 A-frags are
// built from global f32 in K-iters 0-1 (no LDS). Bs single-buffer + reg prefetch.
// LDS ~52.9 KB -> 3 blocks/CU.
__global__ __launch_bounds__(256, 3) void gemm1_kernel(
    const float* __restrict__ points1, const float* __restrict__ points2,
    const int* __restrict__ idxb, const float* __restrict__ wb,
    const u16* __restrict__ wt1b, u16* __restrict__ h1, float* __restrict__ part1) {
    // interp K-tiles: tile stride 2056 u16 (=2048 + 8 pad -> 4-bank stagger/tile)
    __shared__ __align__(16) u16 AiT[8 * 2056];
    __shared__ __align__(16) u16 Bs[8192];         // W1 tile 256x32, XOR-swizzled
    __shared__ int   idxs[192];
    __shared__ float wls[192];
    __shared__ float bsum[256], bsq[256];

    int t = threadIdx.x, bx = blockIdx.x;
    int R0 = bx * 64;
    const float* p2b = points2 + (size_t)(bx >> 7) * SS_PTS * 256;

    if (t < 192) {
        idxs[t] = idxb[(size_t)R0 * 3 + t];
        wls[t]  = wb[(size_t)R0 * 3 + t];
    }
    bsum[t] = 0.0f; bsq[t] = 0.0f;
    __syncthreads();

    int w = t >> 6, l = t & 63;

    // ---- phase 1: wave w stages queries 16w..16w+15; whole wave per row
    {
        int cin = (l & 7) * 4;                    // within-tile channel
        int tile = l >> 3;                        // interp k-tile 0..7
        #pragma unroll 4
        for (int e = 0; e < 16; ++e) {
            int qi = w * 16 + e;
            int i0 = idxs[qi * 3 + 0], i1 = idxs[qi * 3 + 1], i2 = idxs[qi * 3 + 2];
            float w0 = wls[qi * 3 + 0], w1 = wls[qi * 3 + 1], w2 = wls[qi * 3 + 2];
            float4 v0 = *(const float4*)(p2b + (size_t)i0 * 256 + l * 4);
            float4 v1 = *(const float4*)(p2b + (size_t)i1 * 256 + l * 4);
            float4 v2 = *(const float4*)(p2b + (size_t)i2 * 256 + l * 4);
            float o[4] = {
                fmaf(w0, v0.x, fmaf(w1, v1.x, w2 * v2.x)),
                fmaf(w0, v0.y, fmaf(w1, v1.y, w2 * v2.y)),
                fmaf(w0, v0.z, fmaf(w1, v1.z, w2 * v2.z)),
                fmaf(w0, v0.w, fmaf(w1, v1.w, w2 * v2.w))};
            union { u16 u[4]; float2 f; } pk;
            #pragma unroll
            for (int i = 0; i < 4; ++i) pk.u[i] = f2bf(o[i]);
            int sqi = (qi >> 1) & 3;
            int ai = tile * 2056 + qi * 32 + (((cin >> 3) ^ sqi) << 3) + (cin & 7);
            *(float2*)&AiT[ai] = pk.f;
        }
    }

    // ---- B staging: reg prefetch + swizzled LDS write
    int bm = t >> 1, bh = t & 1;
    float4 pb0, pb1, pb2, pb3;
    const u16* wsrc0 = wt1b + (size_t)bm * 320 + bh * 16;
    const u16* wsrc1 = wt1b + (size_t)(bm + 128) * 320 + bh * 16;
    int sb0 = (bm >> 1) & 3, sb1 = ((bm + 128) >> 1) & 3;
    pb0 = ((const float4*)wsrc0)[0]; pb1 = ((const float4*)wsrc0)[1];
    pb2 = ((const float4*)wsrc1)[0]; pb3 = ((const float4*)wsrc1)[1];

    int l15 = l & 15, q = l >> 4;
    int wr = (w >> 1) * 32, wc = (w & 1) * 128;

    f32x4 acc[2][8];
    #pragma unroll
    for (int i = 0; i < 2; ++i)
        #pragma unroll
        for (int j = 0; j < 8; ++j) acc[i][j] = (f32x4){0.f, 0.f, 0.f, 0.f};

    __syncthreads();   // AiT visible

    // ---- phase 2: K-loop (10 x K=32)
    #pragma unroll
    for (int kb = 0; kb < 10; ++kb) {
        *(float4*)&Bs[bm * 32 + (((bh * 2 + 0) ^ sb0) << 3)] = pb0;
        *(float4*)&Bs[bm * 32 + (((bh * 2 + 1) ^ sb0) << 3)] = pb1;
        *(float4*)&Bs[(bm + 128) * 32 + (((bh * 2 + 0) ^ sb1) << 3)] = pb2;
        *(float4*)&Bs[(bm + 128) * 32 + (((bh * 2 + 1) ^ sb1) << 3)] = pb3;
        __syncthreads();
        if (kb < 9) {   // prefetch next B tile (consumed after next barrier)
            const u16* n0 = wsrc0 + (kb + 1) * 32;
            const u16* n1 = wsrc1 + (kb + 1) * 32;
            pb0 = ((const float4*)n0)[0]; pb1 = ((const float4*)n0)[1];
            pb2 = ((const float4*)n1)[0]; pb3 = ((const float4*)n1)[1];
        }
        union uf { float4 f; bf16x8 v; };
        uf af[2], bf8[8];
        #pragma unroll
        for (int fi = 0; fi < 2; ++fi) {
            int ml = wr + fi * 16 + l15;
            if (kb < 2) {
                const float* s = points1 + (size_t)(R0 + ml) * 64 + kb * 32 + q * 8;
                float4 x0 = ((const float4*)s)[0], x1 = ((const float4*)s)[1];
                float va[8] = {x0.x, x0.y, x0.z, x0.w, x1.x, x1.y, x1.z, x1.w};
                af[fi].f = pack8(va);
            } else {
                af[fi].f = *(const float4*)
                    &AiT[(kb - 2) * 2056 + ml * 32 + ((q ^ ((ml >> 1) & 3)) << 3)];
            }
        }
        #pragma unroll
        for (int fj = 0; fj < 8; ++fj) {
            int nl = wc + fj * 16 + l15;
            bf8[fj].f = *(const float4*)&Bs[nl * 32 + ((q ^ ((nl >> 1) & 3)) << 3)];
        }
        #pragma unroll
        for (int fi = 0; fi < 2; ++fi)
            #pragma unroll
            for (int fj = 0; fj < 8; ++fj)
                acc[fi][fj] = __builtin_amdgcn_mfma_f32_16x16x32_bf16(
                    bf8[fj].v, af[fi].v, acc[fi][fj], 0, 0, 0);
        __syncthreads();
    }

    // ---- epilogue: h1 K-tiled store + channel stats
    #pragma unroll
    for (int fi = 0; fi < 2; ++fi) {
        int rg = R0 + wr + fi * 16 + l15;
        #pragma unroll
        for (int fj = 0; fj < 8; ++fj) {
            int c0 = wc + fj * 16 + q * 4;
            union { u16 u[4]; float2 f; } pk;
            #pragma unroll
            for (int i = 0; i < 4; ++i) pk.u[i] = f2bf(acc[fi][fj][i]);
            *(float2*)&h1[((size_t)(c0 >> 5) * 65536 + rg) * 32 + (c0 & 31)] = pk.f;
        }
    }
    #pragma unroll
    for (int fj = 0; fj < 8; ++fj)
        #pragma unroll
        for (int i = 0; i < 4; ++i) {
            int cl = wc + fj * 16 + q * 4 + i;
            float a0 = acc[0][fj][i], a1 = acc[1][fj][i];
            atomicAdd(&bsum[cl], a0 + a1);
            atomicAdd(&bsq[cl], a0 * a0 + a1 * a1);
        }
    __syncthreads();
    part1[(size_t)bx * 512 + t * 2 + 0] = bsum[t];
    part1[(size_t)bx * 512 + t * 2 + 1] = bsq[t];
}

// ---------------------------------------------------------------- stats reduce
__global__ __launch_bounds__(256) void reduce_kernel(
    const float* __restrict__ part, int nblk, int C, float invM,
    const float* __restrict__ gam, const float* __restrict__ bet,
    float* __restrict__ st) {
    __shared__ float red[256];
    int t = threadIdx.x;
    int slot = t & 31, ig = t >> 5;
    int cb = blockIdx.x * 16;
    float p = 0.0f;
    for (int i = ig; i < nblk; i += 8)
        p += part[(size_t)i * (2 * C) + cb * 2 + slot];
    red[t] = p;
    __syncthreads();
    if (t < 32) {
        float tot = red[t];
        #pragma unroll
        for (int k = 1; k < 8; ++k) tot += red[k * 32 + t];
        red[t] = tot;
    }
    __syncthreads();
    if (t < 16) {
        int c = cb + t;
        float sum = red[2 * t], sq = red[2 * t + 1];
        float mean = sum * invM;
        float var  = sq * invM - mean * mean;
        float rs   = rsqrtf(var + 1e-5f);
        float scv  = gam[c] * rs;
        st[c]     = scv;
        st[C + c] = bet[c] - mean * scv;
    }
}

// ---------------------------------------------------------------- GEMM2 v5
// 64x128 tile, grid 1024. LDS double-buffer + reg prefetch, 1 barrier/iter.
__global__ __launch_bounds__(256, 4) void gemm2_kernel(
    const u16* __restrict__ h1, const u16* __restrict__ wt2b,
    const float* __restrict__ st1,
    u16* __restrict__ h2, float* __restrict__ part2) {
    __shared__ __align__(16) u16 As[2][64 * 32];
    __shared__ __align__(16) u16 Bs[2][128 * 32];
    __shared__ float sc1[256], sh1[256];
    __shared__ float bsum[128], bsq[128];

    int t = threadIdx.x;
    int bx = blockIdx.x;
    int R0 = bx * 64;
    sc1[t] = st1[t];
    sh1[t] = st1[256 + t];
    if (t < 128) { bsum[t] = 0.0f; bsq[t] = 0.0f; }

    int w = t >> 6, l = t & 63, l15 = l & 15, q = l >> 4;
    int wr = w * 16;
    int arow = t >> 2, ac8 = (t & 3) << 3, sa = (arow >> 1) & 3;
    int bm = t >> 1, bh = t & 1, sb = (bm >> 1) & 3;

    union lda_t { float4 f; u16 u[8]; };
    lda_t pa; float4 pb0, pb1;
    const u16* bsrc = wt2b + (size_t)bm * 256 + bh * 16;

    // prefetch kb=0
    pa.f = *(const float4*)(h1 + ((size_t)0 * 65536 + R0 + arow) * 32 + ac8);
    pb0 = ((const float4*)bsrc)[0];
    pb1 = ((const float4*)bsrc)[1];

    f32x4 acc[8];
    #pragma unroll
    for (int j = 0; j < 8; ++j) acc[j] = (f32x4){0.f, 0.f, 0.f, 0.f};

    __syncthreads();   // sc1/sh1 visible

    // write buffer 0
    {
        float o[8];
        #pragma unroll
        for (int j = 0; j < 8; ++j)
            o[j] = fmaxf(fmaf(bf2f(pa.u[j]), sc1[ac8 + j], sh1[ac8 + j]), 0.0f);
        *(float4*)&As[0][arow * 32 + (((ac8 >> 3) ^ sa) << 3)] = pack8(o);
        *(float4*)&Bs[0][bm * 32 + (((bh * 2 + 0) ^ sb) << 3)] = pb0;
        *(float4*)&Bs[0][bm * 32 + (((bh * 2 + 1) ^ sb) << 3)] = pb1;
    }
    __syncthreads();

    #pragma unroll
    for (int kb = 0; kb < 8; ++kb) {
        if (kb < 7) {   // prefetch next
            pa.f = *(const float4*)(h1 + ((size_t)(kb + 1) * 65536 + R0 + arow) * 32 + ac8);
            pb0 = ((const float4*)(bsrc + (kb + 1) * 32))[0];
            pb1 = ((const float4*)(bsrc + (kb + 1) * 32))[1];
        }
        int buf = kb & 1;
        union uf { float4 f; bf16x8 v; };
        uf af, bf8[8];
        {
            int ml = wr + l15;
            af.f = *(const float4*)&As[buf][ml * 32 + ((q ^ ((ml >> 1) & 3)) << 3)];
        }
        #pragma unroll
        for (int fj = 0; fj < 8; ++fj) {
            int nl = fj * 16 + l15;
            bf8[fj].f = *(const float4*)&Bs[buf][nl * 32 + ((q ^ ((nl >> 1) & 3)) << 3)];
        }
        #pragma unroll
        for (int fj = 0; fj < 8; ++fj)
            acc[fj] = __builtin_amdgcn_mfma_f32_16x16x32_bf16(
                bf8[fj].v, af.v, acc[fj], 0, 0, 0);
        if (kb < 7) {   // write next buffer (opposite of the one just read)
            int ch0 = (kb + 1) * 32 + ac8;
            float o[8];
            #pragma unroll
            for (int j = 0; j < 8; ++j)
                o[j] = fmaxf(fmaf(bf2f(pa.u[j]), sc1[ch0 + j], sh1[ch0 + j]), 0.0f);
            *(float4*)&As[buf ^ 1][arow * 32 + (((ac8 >> 3) ^ sa) << 3)] = pack8(o);
            *(float4*)&Bs[buf ^ 1][bm * 32 + (((bh * 2 + 0) ^ sb) << 3)] = pb0;
            *(float4*)&Bs[buf ^ 1][bm * 32 + (((bh * 2 + 1) ^ sb) << 3)] = pb1;
        }
        __syncthreads();
    }

    // ---- epilogue: h2 store + stats (shfl-reduce over 16 row-lanes)
    int rg = R0 + wr + l15;
    #pragma unroll
    for (int fj = 0; fj < 8; ++fj) {
        int cl = fj * 16 + q * 4;
        union { u16 u[4]; float2 f; } pk;
        #pragma unroll
        for (int i = 0; i < 4; ++i) pk.u[i] = f2bf(acc[fj][i]);
        *(float2*)&h2[(size_t)rg * 128 + cl] = pk.f;
    }
    #pragma unroll
    for (int fj = 0; fj < 8; ++fj)
        #pragma unroll
        for (int i = 0; i < 4; ++i) {
            float s = acc[fj][i];
            float sq = s * s;
            #pragma unroll
            for (int d = 1; d < 16; d <<= 1) {
                s  += __shfl_xor(s, d, 16);
                sq += __shfl_xor(sq, d, 16);
            }
            if (l15 == 0) {
                int cl = fj * 16 + q * 4 + i;
                atomicAdd(&bsum[cl], s);
                atomicAdd(&bsq[cl], sq);
            }
        }
    __syncthreads();
    if (t < 128) {
        part2[(size_t)bx * 256 + t * 2 + 0] = bsum[t];
        part2[(size_t)bx * 256 + t * 2 + 1] = bsq[t];
    }
}

// ---------------------------------------------------------------- final BN2 + relu
__global__ __launch_bounds__(256) void final_kernel(
    const u16* __restrict__ h2, const float* __restrict__ st2,
    float* __restrict__ out) {
    __shared__ float lst[256];
    int t = threadIdx.x;
    lst[t] = st2[t];
    __syncthreads();
    size_t e0 = ((size_t)blockIdx.x * 256 + t) * 8;
    int c0 = (int)(e0 & 127);
    union { float4 f; u16 u[8]; } ld;
    ld.f = *(const float4*)(h2 + e0);
    float o[8];
    #pragma unroll
    for (int j = 0; j < 8; ++j) {
        int c = c0 + j;
        float v = fmaf(bf2f(ld.u[j]), lst[c], lst[128 + c]);
        o[j] = fmaxf(v, 0.0f);
    }
    float4* op = (float4*)(out + e0);
    float4 r0; r0.x = o[0]; r0.y = o[1]; r0.z = o[2]; r0.w = o[3];
    float4 r1; r1.x = o[4]; r1.y = o[5]; r1.z = o[6]; r1.w = o[7];
    op[0] = r0;
    op[1] = r1;
}

// ----------------------------------------------------------------
extern "C" void kernel_launch(void* const* d_in, const int* in_sizes, int n_in,
                              void* d_out, int out_size, void* d_ws, size_t ws_size,
                              hipStream_t stream) {
    (void)in_sizes; (void)n_in; (void)out_size; (void)ws_size;
    const float* xyz1    = (const float*)d_in[0];
    const float* xyz2    = (const float*)d_in[1];
    const float* points1 = (const float*)d_in[2];
    const float* points2 = (const float*)d_in[3];
    const float* W1      = (const float*)d_in[4];
    const float* g1      = (const float*)d_in[5];
    const float* b1      = (const float*)d_in[6];
    const float* W2      = (const float*)d_in[7];
    const float* g2      = (const float*)d_in[8];
    const float* b2      = (const float*)d_in[9];

    char* ws = (char*)d_ws;
    int*   idxb = (int*)(ws + OFF_IDX);
    float* wb   = (float*)(ws + OFF_W);
    u16*   wt1b = (u16*)(ws + OFF_WT1B);
    u16*   wt2b = (u16*)(ws + OFF_WT2B);
    float* st1  = (float*)(ws + OFF_ST1);
    float* st2  = (float*)(ws + OFF_ST2);
    float* p1   = (float*)(ws + OFF_P1);
    float* p2   = (float*)(ws + OFF_P2);
    u16*   h1   = (u16*)(ws + OFF_H1);
    u16*   h2   = (u16*)(ws + OFF_H2);
    float* outp = (float*)d_out;

    prep_kernel<<<320, 256, 0, stream>>>(W1, W2, wt1b, wt2b);
    knn_kernel<<<1024, 256, 0, stream>>>(xyz1, xyz2, idxb, wb);
    gemm1_kernel<<<1024, 256, 0, stream>>>(points1, points2, idxb, wb, wt1b, h1, p1);
    reduce_kernel<<<16, 256, 0, stream>>>(p1, 1024, 256, 1.0f / 65536.0f, g1, b1, st1);
    gemm2_kernel<<<1024, 256, 0, stream>>>(h1, wt2b, st1, h2, p2);
    reduce_kernel<<<8, 256, 0, stream>>>(p2, 1024, 128, 1.0f / 65536.0f, g2, b2, st2);
    final_kernel<<<4096, 256, 0, stream>>>(h2, st2, outp);
}